// Round 4
// baseline (655.746 us; speedup 1.0000x reference)
//
#include <hip/hip_runtime.h>

#define T_LEN 256
#define D_IN 4
#define HID 16

struct CellW { const float *Wih, *Whh, *bih, *bhh; };
struct Params { CellW c[6]; const float* y; float* hout; };

__device__ __forceinline__ float fexp2(float x) { return __builtin_amdgcn_exp2f(x); }
__device__ __forceinline__ float frcp(float x)  { return __builtin_amdgcn_rcpf(x); }

// v_fmac_f32 with DPP row_ror:N applied to src0 (h). Weights are pre-permuted
// at init with the SAME dpp ctrl, so direction semantics are self-consistent.
#define FMAC_ROR(acc, hv, wv, N) \
    asm volatile("v_fmac_f32_dpp %0, %1, %2 row_ror:" #N " row_mask:0xf bank_mask:0xf" \
                 : "+v"(acc) : "v"(hv), "v"(wv))

// 16x16 matvec: acc += W_row(lane) . h, h distributed one value per lane of
// each 16-lane DPP row. 16 fmacs, two accumulators to break dep chains.
// s_nop 1 guards the gfx9 "VALU write -> DPP read needs 2 wait states" hazard.
__device__ __forceinline__ void matvec16(float& a0, float& a1, float h, const float (&w)[16]) {
    asm volatile("s_nop 1");
    asm volatile("v_fmac_f32 %0, %1, %2" : "+v"(a0) : "v"(h), "v"(w[0]));
    FMAC_ROR(a1, h, w[1], 1);
    FMAC_ROR(a0, h, w[2], 2);
    FMAC_ROR(a1, h, w[3], 3);
    FMAC_ROR(a0, h, w[4], 4);
    FMAC_ROR(a1, h, w[5], 5);
    FMAC_ROR(a0, h, w[6], 6);
    FMAC_ROR(a1, h, w[7], 7);
    FMAC_ROR(a0, h, w[8], 8);
    FMAC_ROR(a1, h, w[9], 9);
    FMAC_ROR(a0, h, w[10], 10);
    FMAC_ROR(a1, h, w[11], 11);
    FMAC_ROR(a0, h, w[12], 12);
    FMAC_ROR(a1, h, w[13], 13);
    FMAC_ROR(a0, h, w[14], 14);
    FMAC_ROR(a1, h, w[15], 15);
}

template<int N> __device__ __forceinline__ int ror16(int v) {
    return __builtin_amdgcn_update_dpp(0, v, 0x120 + N, 0xF, 0xF, true);
}

// pre is the raw gate pre-activation; kmul = -log2e (sigmoid rows) or
// -2log2e (g rows). act = rmul * 1/(1+exp2(pre*kmul)) + radd.
__device__ __forceinline__ void act_update(float pre, float kmul, float rmul, float radd,
                                           int ai, int af, int ag, int ao,
                                           float& c, float& h) {
    float e = fexp2(pre * kmul);
    float s = frcp(1.f + e);
    float act = fmaf(rmul, s, radd);
    int av = __float_as_int(act);
    float gi = __int_as_float(__builtin_amdgcn_ds_bpermute(ai, av));
    float gf = __int_as_float(__builtin_amdgcn_ds_bpermute(af, av));
    float gg = __int_as_float(__builtin_amdgcn_ds_bpermute(ag, av));
    float go = __int_as_float(__builtin_amdgcn_ds_bpermute(ao, av));
    c = fmaf(gf, c, gi * gg);
    float e2 = fexp2(c * 2.8853900817779268f);            // 2*log2e*c
    float th = fmaf(-2.f, frcp(1.f + e2), 1.f);           // tanh(c)
    h = go * th;
}

// Occupancy cap via LDS: 48KB/block -> floor(160/48)=3 blocks/CU = 3 waves/EU.
// LLVM's register-budget heuristic honors the LDS occupancy limit (unlike the
// bare waves_per_eu attr in rounds 2-3, where the allocator kept a 64-VGPR /
// 8-wave target and spilled ~50 live values to AGPRs -> ~2x VALU inflation).
// Budget at 3 waves/EU = ~168 VGPRs; live set ~116 fits with slack.
#define LDS_PAD_BYTES 49152

__global__ void
__attribute__((amdgpu_flat_work_group_size(256, 256), amdgpu_waves_per_eu(3, 3)))
lstm_chain_kernel(Params p)
{
    volatile __shared__ float lds_pad[LDS_PAD_BYTES / 4];

    const int lane = threadIdx.x & 63;
    const int wid  = blockIdx.x * (blockDim.x >> 6) + (threadIdx.x >> 6);
    const int b    = wid >> 1;
    const int dir  = wid & 1;
    const int j    = lane & 15;          // hidden unit (position within DPP row)
    const int gate = lane >> 4;          // 0=i 1=f 2=g 3=o
    const int r    = lane;               // weight row == lane (torch gate order)

    const CellW c1 = p.c[dir * 3 + 0];
    const CellW c2 = p.c[dir * 3 + 1];
    const CellW c3 = p.c[dir * 3 + 2];

    // per-lane activation constants (g-gate lanes do tanh = 2*sigmoid(2x)-1)
    const bool  isg  = (gate == 2);
    const float kmul = isg ? -2.8853900817779268f : -1.4426950408889634f;
    const float rmul = isg ? 2.f : 1.f;
    const float radd = isg ? -1.f : 0.f;

    // keep the LDS pad alive (one volatile store; never read)
    if (threadIdx.x == 0) lds_pad[0] = kmul;

    // source-lane j for each row_ror:i (self-consistent with FMAC_ROR)
    int js[16];
    js[0]  = j;
    js[1]  = ror16<1>(j);  js[2]  = ror16<2>(j);  js[3]  = ror16<3>(j);
    js[4]  = ror16<4>(j);  js[5]  = ror16<5>(j);  js[6]  = ror16<6>(j);
    js[7]  = ror16<7>(j);  js[8]  = ror16<8>(j);  js[9]  = ror16<9>(j);
    js[10] = ror16<10>(j); js[11] = ror16<11>(j); js[12] = ror16<12>(j);
    js[13] = ror16<13>(j); js[14] = ror16<14>(j); js[15] = ror16<15>(j);

    // per-lane weights (84 floats), rotation-permuted, raw (absmax ~2.4e-4)
    float wih1[D_IN], whh1[HID], wih2[HID], whh2[HID], wih3[HID], whh3[HID];
    {
        const float* q = c1.Wih + r * D_IN;
#pragma unroll
        for (int k = 0; k < D_IN; ++k) wih1[k] = q[k];
    }
    {
        const float* q1 = c1.Whh + r * HID;
        const float* q2 = c2.Wih + r * HID;
        const float* q3 = c2.Whh + r * HID;
        const float* q4 = c3.Wih + r * HID;
        const float* q5 = c3.Whh + r * HID;
#pragma unroll
        for (int i = 0; i < HID; ++i) {
            const int s = js[i];
            whh1[i] = q1[s];
            wih2[i] = q2[s];
            whh2[i] = q3[s];
            wih3[i] = q4[s];
            whh3[i] = q5[s];
        }
    }
    const float bias1 = c1.bih[r] + c1.bhh[r];
    const float bias2 = c2.bih[r] + c2.bhh[r];
    const float bias3 = c3.bih[r] + c3.bhh[r];

    // bpermute byte-addresses for gate gather (i,f,g,o of unit j)
    const int ai = 4 * j;
    const int af = 4 * (16 + j);
    const int ag = 4 * (32 + j);
    const int ao = 4 * (48 + j);

    // state (distributed: lane holds value for unit j, replicated across rows)
    float cc1 = 0.f, cc2 = 0.f, cc3 = 0.f;
    float h1 = 0.f, h2 = 0.f, h3 = 0.f;

    const float* ybase = p.y + (size_t)b * (T_LEN * D_IN);
    const int xstep = dir ? -D_IN : D_IN;
    const float* xp = ybase + (dir ? (T_LEN - 1) * D_IN : 0);
    float4 xv = *(const float4*)xp;

#pragma unroll 1
    for (int t = 0; t < T_LEN; ++t) {
        // prefetch next x (uniform address; dummy in-range read on last iter)
        const float* xpn = (t + 1 < T_LEN) ? (xp + xstep) : ybase;
        float4 xn = *(const float4*)xpn;

        // ---- cell 1 ----
        {
            float a0 = bias1, a1 = 0.f;
            matvec16(a0, a1, h1, whh1);          // recurrence (h1 is old)
            a0 = fmaf(xv.x, wih1[0], a0);
            a1 = fmaf(xv.y, wih1[1], a1);
            a0 = fmaf(xv.z, wih1[2], a0);
            a1 = fmaf(xv.w, wih1[3], a1);
            act_update(a0 + a1, kmul, rmul, radd, ai, af, ag, ao, cc1, h1);
        }
        // ---- cell 2 ----
        {
            float a0 = bias2, a1 = 0.f;
            matvec16(a0, a1, h2, whh2);          // recurrence first (h2 old)
            matvec16(a0, a1, h1, wih2);          // input (h1 fresh; s_nop guard)
            act_update(a0 + a1, kmul, rmul, radd, ai, af, ag, ao, cc2, h2);
        }
        // ---- cell 3 ----
        {
            float a0 = bias3, a1 = 0.f;
            matvec16(a0, a1, h3, whh3);
            matvec16(a0, a1, h2, wih3);
            act_update(a0 + a1, kmul, rmul, radd, ai, af, ag, ao, cc3, h3);
        }

        xv = xn; xp = xpn;
    }

    if (lane < 16) p.hout[(size_t)b * 32 + dir * HID + j] = h3;
}

__global__ void out_proj_kernel(const float* __restrict__ ws,
                                const float* __restrict__ Wout,
                                const float* __restrict__ bout,
                                float* __restrict__ out, int B)
{
    int idx = blockIdx.x * blockDim.x + threadIdx.x;
    if (idx >= B * 4) return;
    int b = idx >> 2, o = idx & 3;
    float acc = bout[o];
    const float* h = ws + (size_t)b * 32;
    const float* w = Wout + o * 32;
#pragma unroll
    for (int m = 0; m < 32; ++m) acc = fmaf(h[m], w[m], acc);
    out[idx] = acc;
}

extern "C" void kernel_launch(void* const* d_in, const int* in_sizes, int n_in,
                              void* d_out, int out_size, void* d_ws, size_t ws_size,
                              hipStream_t stream)
{
    const int B = in_sizes[0] / (T_LEN * D_IN); // 4096

    Params p;
    for (int s = 0; s < 6; ++s) {
        p.c[s].Wih = (const float*)d_in[1 + 4 * s];
        p.c[s].Whh = (const float*)d_in[2 + 4 * s];
        p.c[s].bih = (const float*)d_in[3 + 4 * s];
        p.c[s].bhh = (const float*)d_in[4 + 4 * s];
    }
    p.y = (const float*)d_in[0];
    p.hout = (float*)d_ws;

    const int waves = B * 2;               // one wave per (batch, direction)
    const int blocks = waves / 4;          // 4 waves per 256-thread block
    lstm_chain_kernel<<<blocks, 256, 0, stream>>>(p);

    const float* Wout = (const float*)d_in[25];
    const float* bout = (const float*)d_in[26];
    out_proj_kernel<<<(B * 4 + 255) / 256, 256, 0, stream>>>(
        (const float*)d_ws, Wout, bout, (float*)d_out, B);
}

// Round 6
// 375.553 us; speedup vs baseline: 1.7461x; 1.7461x over previous
//
#include <hip/hip_runtime.h>

#define T_LEN 256
#define D_IN 4
#define HID 16

typedef _Float16 half8 __attribute__((ext_vector_type(8)));
typedef float float4v __attribute__((ext_vector_type(4)));

struct CellW { const float *Wih, *Whh, *bih, *bhh; };
struct Params { CellW c[6]; const float* y; float* hout; };

__device__ __forceinline__ float fexp2(float x) { return __builtin_amdgcn_exp2f(x); }
__device__ __forceinline__ float frcp(float x)  { return __builtin_amdgcn_rcpf(x); }

// Scheduling fence: keep ds_write(h) ... ds_read(A) in program order; the
// per-wave LDS pipe is FIFO, so an in-order read sees the write. Data
// completion waits (lgkmcnt) are inserted by the compiler before use.
#define SCHED_FENCE() asm volatile("" ::: "memory")

// sigmoid: pre already scaled by -log2e  -> 1/(1+exp2(pre))
// tanh(g): pre already scaled by -2log2e -> 2/(1+exp2(pre)) - 1
// Per-accumulator gate type is compile-time uniform: no divergence.
__device__ __forceinline__ void cell_act(const float4v& pi, const float4v& pf,
                                         const float4v& pg, const float4v& po,
                                         float4v& c, float h[4]) {
#pragma unroll
    for (int r = 0; r < 4; ++r) {
        float i = frcp(1.f + fexp2(pi[r]));
        float f = frcp(1.f + fexp2(pf[r]));
        float g = fmaf(2.f, frcp(1.f + fexp2(pg[r])), -1.f);
        float o = frcp(1.f + fexp2(po[r]));
        float cn = fmaf(f, c[r], i * g);
        c[r] = cn;
        // tanh(cn) = 1 - 2/(1+exp2(2*log2e*cn))
        float th = fmaf(-2.f, frcp(1.f + fexp2(cn * 2.8853900817779268f)), 1.f);
        h[r] = o * th;
    }
}

#define MFMA(a, b, c) __builtin_amdgcn_mfma_f32_16x16x32_f16(a, b, c, 0, 0, 0)

// LDS layout (halfs): X0[16x16]=0, X1=256, H1=512, H2=768, H3=1024. Rows are
// 16 halfs (32B): batch-row for H (16 units), k-row for X (k=0..3 x, 4..15 =0).
#define LDS_X0 0
#define LDS_X1 256
#define LDS_H1 512
#define LDS_H2 768
#define LDS_H3 1024

__global__ void __launch_bounds__(64)
lstm_chain_kernel(Params p)
{
    __shared__ _Float16 lds[1280];

    const int L   = threadIdx.x & 63;
    const int tid = blockIdx.x;          // tile id: 16 chains
    const int dir = tid & 1;
    const int b0  = (tid >> 1) * 16;
    const int n    = L & 15;             // B: gate-col / D: unit / A: batch
    const int quad = L >> 4;
    const int koff = quad * 8;           // A/B k-offset for this lane

    const CellW c1 = p.c[dir * 3 + 0];
    const CellW c2 = p.c[dir * 3 + 1];
    const CellW c3 = p.c[dir * 3 + 2];

    // ---- B fragments (weights), scale folded in; bias as MFMA C operand ----
    half8  B1[4], B2[4], B3[4];
    float4v bias1[4], bias2[4], bias3[4];
    const float LOG2E = 1.4426950408889634f;
#pragma unroll
    for (int g = 0; g < 4; ++g) {
        const float s = (g == 2) ? -2.f * LOG2E : -LOG2E;
        const int row = g * 16 + n;      // torch gate order i,f,g,o
        half8 f1, f2, f3;
#pragma unroll
        for (int j = 0; j < 8; ++j) {
            const int k = koff + j;
            float v1 = (k < 16) ? ((k < D_IN) ? c1.Wih[row * D_IN + k] : 0.f)
                                : c1.Whh[row * 16 + (k - 16)];
            float v2 = (k < 16) ? c2.Wih[row * 16 + k] : c2.Whh[row * 16 + (k - 16)];
            float v3 = (k < 16) ? c3.Wih[row * 16 + k] : c3.Whh[row * 16 + (k - 16)];
            f1[j] = (_Float16)(v1 * s);
            f2[j] = (_Float16)(v2 * s);
            f3[j] = (_Float16)(v3 * s);
        }
        B1[g] = f1; B2[g] = f2; B3[g] = f3;
        float b1v = (c1.bih[row] + c1.bhh[row]) * s;
        float b2v = (c2.bih[row] + c2.bhh[row]) * s;
        float b3v = (c3.bih[row] + c3.bhh[row]) * s;
        bias1[g] = (float4v){b1v, b1v, b1v, b1v};
        bias2[g] = (float4v){b2v, b2v, b2v, b2v};
        bias3[g] = (float4v){b3v, b3v, b3v, b3v};
    }

    // ---- addresses ----
    const int rowoff = n * 16 + (quad & 1) * 8;             // halfs, 16B-aligned
    const int a1h0 = ((L < 32) ? LDS_X0 : LDS_H1) + rowoff;
    const int a1h1 = ((L < 32) ? LDS_X1 : LDS_H1) + rowoff;
    const int a2h  = ((L < 32) ? LDS_H1 : LDS_H2) + rowoff;
    const int a3h  = ((L < 32) ? LDS_H2 : LDS_H3) + rowoff;
    const int hwb  = quad * 64 + n;                          // h-write base (halfs)

    // ---- init: zero LDS (X pads + H = initial h=0), stage x(t=0) ----
    {
        int* l4 = (int*)lds;
#pragma unroll
        for (int i = 0; i < 10; ++i) l4[L + 64 * i] = 0;
    }
    const float* ybase = p.y + (size_t)(b0) * (T_LEN * D_IN);
    const int tt0 = dir ? (T_LEN - 1) : 0;
    if (L < 16) {
        const float4 xv = *(const float4*)(ybase + ((size_t)L * T_LEN + tt0) * D_IN);
        lds[LDS_X0 + L * 16 + 0] = (_Float16)xv.x;
        lds[LDS_X0 + L * 16 + 1] = (_Float16)xv.y;
        lds[LDS_X0 + L * 16 + 2] = (_Float16)xv.z;
        lds[LDS_X0 + L * 16 + 3] = (_Float16)xv.w;
    }
    SCHED_FENCE();

    float4v cc1 = {0.f, 0.f, 0.f, 0.f};
    float4v cc2 = {0.f, 0.f, 0.f, 0.f};
    float4v cc3 = {0.f, 0.f, 0.f, 0.f};
    float h1[4], h2[4], h3[4];

    half8 a1 = *(const half8*)&lds[a1h0];

#pragma unroll 1
    for (int t = 0; t < T_LEN; ++t) {
        // prefetch x(t+1) from global (consumed after cell1)
        const int tn = (t + 1 < T_LEN) ? (t + 1) : (T_LEN - 1);
        const int ttn = dir ? (T_LEN - 1 - tn) : tn;
        float4 xv;
        if (L < 16)
            xv = *(const float4*)(ybase + ((size_t)L * T_LEN + ttn) * D_IN);

        // ---- cell 1 ----
        {
            float4v gi = MFMA(a1, B1[0], bias1[0]);
            float4v gf = MFMA(a1, B1[1], bias1[1]);
            float4v gg = MFMA(a1, B1[2], bias1[2]);
            float4v go = MFMA(a1, B1[3], bias1[3]);
            cell_act(gi, gf, gg, go, cc1, h1);
        }
#pragma unroll
        for (int r = 0; r < 4; ++r) lds[LDS_H1 + hwb + r * 16] = (_Float16)h1[r];
        SCHED_FENCE();

        // stage x(t+1) into the alternate X slab
        if (L < 16) {
            const int xb = ((t + 1) & 1) ? LDS_X1 : LDS_X0;
            lds[xb + L * 16 + 0] = (_Float16)xv.x;
            lds[xb + L * 16 + 1] = (_Float16)xv.y;
            lds[xb + L * 16 + 2] = (_Float16)xv.z;
            lds[xb + L * 16 + 3] = (_Float16)xv.w;
        }
        SCHED_FENCE();
        // A1 for t+1 (X alt + fresh H1): issued early to hide LDS latency
        half8 a1n = *(const half8*)&lds[((t + 1) & 1) ? a1h1 : a1h0];
        // A2 = [h1 new | h2 old]
        half8 a2 = *(const half8*)&lds[a2h];

        // ---- cell 2 ----
        {
            float4v gi = MFMA(a2, B2[0], bias2[0]);
            float4v gf = MFMA(a2, B2[1], bias2[1]);
            float4v gg = MFMA(a2, B2[2], bias2[2]);
            float4v go = MFMA(a2, B2[3], bias2[3]);
            cell_act(gi, gf, gg, go, cc2, h2);
        }
#pragma unroll
        for (int r = 0; r < 4; ++r) lds[LDS_H2 + hwb + r * 16] = (_Float16)h2[r];
        SCHED_FENCE();
        // A3 = [h2 new | h3 old]
        half8 a3 = *(const half8*)&lds[a3h];

        // ---- cell 3 ----
        {
            float4v gi = MFMA(a3, B3[0], bias3[0]);
            float4v gf = MFMA(a3, B3[1], bias3[1]);
            float4v gg = MFMA(a3, B3[2], bias3[2]);
            float4v go = MFMA(a3, B3[3], bias3[3]);
            cell_act(gi, gf, gg, go, cc3, h3);
        }
#pragma unroll
        for (int r = 0; r < 4; ++r) lds[LDS_H3 + hwb + r * 16] = (_Float16)h3[r];
        SCHED_FENCE();

        a1 = a1n;
    }

    // final h3 (regs): lane L reg r -> batch b0+quad*4+r, unit n
#pragma unroll
    for (int r = 0; r < 4; ++r)
        p.hout[(size_t)(b0 + quad * 4 + r) * 32 + dir * HID + n] = h3[r];
}

__global__ void out_proj_kernel(const float* __restrict__ ws,
                                const float* __restrict__ Wout,
                                const float* __restrict__ bout,
                                float* __restrict__ out, int B)
{
    int idx = blockIdx.x * blockDim.x + threadIdx.x;
    if (idx >= B * 4) return;
    int b = idx >> 2, o = idx & 3;
    float acc = bout[o];
    const float* h = ws + (size_t)b * 32;
    const float* w = Wout + o * 32;
#pragma unroll
    for (int m = 0; m < 32; ++m) acc = fmaf(h[m], w[m], acc);
    out[idx] = acc;
}

extern "C" void kernel_launch(void* const* d_in, const int* in_sizes, int n_in,
                              void* d_out, int out_size, void* d_ws, size_t ws_size,
                              hipStream_t stream)
{
    const int B = in_sizes[0] / (T_LEN * D_IN); // 4096

    Params p;
    for (int s = 0; s < 6; ++s) {
        p.c[s].Wih = (const float*)d_in[1 + 4 * s];
        p.c[s].Whh = (const float*)d_in[2 + 4 * s];
        p.c[s].bih = (const float*)d_in[3 + 4 * s];
        p.c[s].bhh = (const float*)d_in[4 + 4 * s];
    }
    p.y = (const float*)d_in[0];
    p.hout = (float*)d_ws;

    const int tiles = (B / 16) * 2;          // 16 chains per wave, both dirs
    lstm_chain_kernel<<<tiles, 64, 0, stream>>>(p);

    const float* Wout = (const float*)d_in[25];
    const float* bout = (const float*)d_in[26];
    out_proj_kernel<<<(B * 4 + 255) / 256, 256, 0, stream>>>(
        (const float*)d_ws, Wout, bout, (float*)d_out, B);
}